// Round 10
// baseline (484.579 us; speedup 1.0000x reference)
//
#include <hip/hip_runtime.h>

#define TT 2048
#define BB 8
#define DD 1024
#define NN 64
#define CH 64              // timesteps per Gram chunk (= lanes)
#define NCH (TT / CH)      // 32

typedef __attribute__((ext_vector_type(8))) short bfrag;    // 8 bf16 (4 VGPRs)
typedef __attribute__((ext_vector_type(4))) float f32x4;    // MFMA C/D
typedef __attribute__((ext_vector_type(8))) unsigned short ushort8;

// fast sigmoid: v_exp + v_add + v_rcp (no IEEE div sequence)
__device__ __forceinline__ float sigmoidf_(float x) {
    return __builtin_amdgcn_rcpf(1.0f + __expf(-x));
}

// f32 -> bf16 round-to-nearest-even
__device__ __forceinline__ unsigned short cvt_bf16(float f) {
    unsigned int u = __float_as_uint(f);
    return (unsigned short)((u + 0x7FFF + ((u >> 16) & 1)) >> 16);
}
__device__ __forceinline__ unsigned int pack_bf16x2(float a, float b) {
    return (unsigned int)cvt_bf16(a) | ((unsigned int)cvt_bf16(b) << 16);
}
__device__ __forceinline__ float bf2f(unsigned short u) {
    return __uint_as_float((unsigned int)u << 16);
}

__device__ __forceinline__ float rdlane(float x, int l) {
    return __int_as_float(__builtin_amdgcn_readlane(__float_as_int(x), l));
}

// async global->LDS, 16 B/lane (per-lane global addr, wave-uniform LDS base)
__device__ __forceinline__ void gll16(const void* g, void* l) {
    __builtin_amdgcn_global_load_lds(
        (const __attribute__((address_space(1))) void*)g,
        (__attribute__((address_space(3))) void*)l, 16, 0, 0);
}

// ---------------------------------------------------------------------------
// Phase 1: projections via bf16 MFMA (unchanged from R6, known good).
// ---------------------------------------------------------------------------
__global__ __launch_bounds__(256) void proj_gemm_kernel(
    const float* __restrict__ x,
    const float* __restrict__ W0, const float* __restrict__ W1,
    const float* __restrict__ W2, const float* __restrict__ W3,
    const float* __restrict__ b_alpha,
    float* __restrict__ O0, float* __restrict__ O1,
    float* __restrict__ O2, float* __restrict__ O3)
{
    const int mat = blockIdx.x;
    const float* __restrict__ W = (mat == 0) ? W0 : (mat == 1) ? W1 : (mat == 2) ? W2 : W3;
    float* __restrict__ C       = (mat == 0) ? O0 : (mat == 1) ? O1 : (mat == 2) ? O2 : O3;

    const int m0   = blockIdx.y * 128;
    const int tid  = threadIdx.x;
    const int lane = tid & 63;
    const int wave = tid >> 6;
    const int ln   = lane & 15;
    const int q8   = (lane >> 4) * 8;

    __shared__ unsigned short As[128][40];
    __shared__ unsigned short Bs[64][40];

    f32x4 acc[2][4] = {};

    const int arow = tid >> 1;
    const int aseg = (tid & 1) * 16;

    float4 pa[4], pb[4];
    {
        const float* ap = &x[(size_t)(m0 + arow) * DD + aseg];
        #pragma unroll
        for (int j = 0; j < 4; j++) pa[j] = *(const float4*)(ap + 4 * j);
        if (tid < 128) {
            const float* bp = &W[(size_t)arow * DD + aseg];
            #pragma unroll
            for (int j = 0; j < 4; j++) pb[j] = *(const float4*)(bp + 4 * j);
        }
    }

    for (int k0 = 0; k0 < DD; k0 += 32) {
        __syncthreads();
        {
            unsigned short t16[16];
            const float* pf = (const float*)pa;
            #pragma unroll
            for (int j = 0; j < 16; j++) t16[j] = cvt_bf16(pf[j]);
            *(ushort8*)&As[arow][aseg]     = *(ushort8*)&t16[0];
            *(ushort8*)&As[arow][aseg + 8] = *(ushort8*)&t16[8];
            if (tid < 128) {
                const float* qf = (const float*)pb;
                #pragma unroll
                for (int j = 0; j < 16; j++) t16[j] = cvt_bf16(qf[j]);
                *(ushort8*)&Bs[arow][aseg]     = *(ushort8*)&t16[0];
                *(ushort8*)&Bs[arow][aseg + 8] = *(ushort8*)&t16[8];
            }
        }
        if (k0 + 32 < DD) {
            const float* ap = &x[(size_t)(m0 + arow) * DD + k0 + 32 + aseg];
            #pragma unroll
            for (int j = 0; j < 4; j++) pa[j] = *(const float4*)(ap + 4 * j);
            if (tid < 128) {
                const float* bp = &W[(size_t)arow * DD + k0 + 32 + aseg];
                #pragma unroll
                for (int j = 0; j < 4; j++) pb[j] = *(const float4*)(bp + 4 * j);
            }
        }
        __syncthreads();

        bfrag af[2], bf[4];
        #pragma unroll
        for (int mt = 0; mt < 2; mt++)
            af[mt] = *(const bfrag*)&As[wave * 32 + mt * 16 + ln][q8];
        #pragma unroll
        for (int nt = 0; nt < 4; nt++)
            bf[nt] = *(const bfrag*)&Bs[nt * 16 + ln][q8];
        #pragma unroll
        for (int mt = 0; mt < 2; mt++)
            #pragma unroll
            for (int nt = 0; nt < 4; nt++)
                acc[mt][nt] = __builtin_amdgcn_mfma_f32_16x16x32_bf16(
                    af[mt], bf[nt], acc[mt][nt], 0, 0, 0);
    }

    #pragma unroll
    for (int nt = 0; nt < 4; nt++) {
        const int col = nt * 16 + ln;
        const float ba = (mat == 3) ? b_alpha[col] : 0.0f;
        #pragma unroll
        for (int mt = 0; mt < 2; mt++) {
            #pragma unroll
            for (int r = 0; r < 4; r++) {
                const int row = m0 + wave * 32 + mt * 16 + (lane >> 4) * 4 + r;
                float v = acc[mt][nt][r];
                if (mat == 3) v = sigmoidf_(v + ba);
                C[(size_t)row * NN + col] = v;
            }
        }
    }
}

// ---------------------------------------------------------------------------
// Phase 1.5a: prep. w = (1-alpha)*v, in place over v_all.
// ---------------------------------------------------------------------------
__global__ __launch_bounds__(256) void prep_kernel(
    float* __restrict__ v_all, const float* __restrict__ a_all)
{
    const size_t i = (size_t)blockIdx.x * 256 + threadIdx.x;
    v_all[i] = (1.0f - a_all[i]) * v_all[i];
}

// ---------------------------------------------------------------------------
// Phase 1.5b: per-(batch,chunk) Gram matrices, bf16.
//   G [u][t] = k_u . k_t     Gq[u][t] = k_u . q_t     (u,t within chunk)
// grid = (NCH, BB), block 256.
// ---------------------------------------------------------------------------
__global__ __launch_bounds__(256) void gram_kernel(
    const float* __restrict__ k_all, const float* __restrict__ q_all,
    unsigned short* __restrict__ G_all, unsigned short* __restrict__ Gq_all)
{
    const int c   = blockIdx.x;
    const int b   = blockIdx.y;
    const int tid = threadIdx.x;

    __shared__ float kc[CH][65];
    __shared__ float qc[CH][65];

    #pragma unroll
    for (int j = 0; j < 16; ++j) {
        const int e = tid + 256 * j;          // 0..4095
        const int row = e >> 6, col = e & 63;
        const size_t g = ((size_t)(c * CH + row) * BB + b) * NN + col;
        kc[row][col] = k_all[g];
        qc[row][col] = q_all[g];
    }
    __syncthreads();

    unsigned short* Gb  = G_all  + ((size_t)b * NCH + c) * CH * CH;
    unsigned short* Gqb = Gq_all + ((size_t)b * NCH + c) * CH * CH;

    #pragma unroll
    for (int m = 0; m < 16; ++m) {
        const int e = tid * 16 + m;           // 0..4095
        const int u = e >> 6, t = e & 63;
        float s1 = 0.f, s2 = 0.f;
        #pragma unroll 8
        for (int j = 0; j < CH; ++j) {
            s1 = fmaf(kc[u][j], kc[t][j], s1);
            s2 = fmaf(kc[u][j], qc[t][j], s2);
        }
        Gb[e]  = cvt_bf16(s1);
        Gqb[e] = cvt_bf16(s2);
    }
}

// ---------------------------------------------------------------------------
// Phase 2: scan via chunked Gram reformulation. One row-chain per wave,
// lane = state column = step-in-chunk. Within a chunk (frame: S0 = chunk
// start, A = running prod of a, all per row):
//   retrieved_t = A_{t-1} * B0[t] + acc_d[t]
//   acc_d = a_t*acc_d + c_t*G[t][:]     (ONE fma per step, no reduction)
//   acc_q = a_t*acc_q + c_t*Gq[t][:] ;  out_t = A_t*qB0[t] + acc_q[t]
//   acc_S = a_t*acc_S + c_t*k_t[:]   ;  S_end = A*S0 + acc_S
// B0[t] = S0.k_t, qB0[t] = S0.q_t computed per chunk as column-matvecs
// (readlane-broadcast of S, conflict-free padded k/q). G/Gq precomputed
// (S-independent). grid = (B, 8) = 64 blocks x 512 thr (8 rows/block).
// ---------------------------------------------------------------------------
__global__ __launch_bounds__(512) void scan_kernel(
    const float* __restrict__ k_all, const float* __restrict__ q_all,
    const float* __restrict__ w_all, const float* __restrict__ a_all,
    const unsigned short* __restrict__ G_all,
    const unsigned short* __restrict__ Gq_all,
    const float* __restrict__ S0g,
    const float* __restrict__ d_g, const float* __restrict__ b_g,
    float* __restrict__ out, float* __restrict__ S_final)
{
    const int b    = blockIdx.x;
    const int r0   = blockIdx.y * 8;
    const int tid  = threadIdx.x;
    const int lane = tid & 63;
    const int wave = tid >> 6;     // 0..7 = row within block
    const int row  = r0 + wave;

    __shared__ unsigned short Gs [2][CH * CH];   // bf16, 16 KB
    __shared__ unsigned short Gqs[2][CH * CH];   // 16 KB
    __shared__ unsigned short ksb[CH * 68];      // bf16 rows padded, 8.5 KB
    __shared__ unsigned short qsb[CH * 68];      // 8.5 KB
    __shared__ float asl[2][CH * 8];             // 4 KB
    __shared__ float wsl[2][CH * 8];             // 4 KB   (total ~57 KB)

    float S = S0g[((size_t)b * NN + row) * NN + lane];
    const float ndg = -d_g[row];
    const float nbg = -b_g[row];

    // --- staging: G/Gq/a/w via gll16 (double-buffered) ---
    auto stage_G = [&](int chunk, int dbuf) {
        const unsigned short* gs =
            G_all + ((size_t)b * NCH + chunk) * CH * CH + wave * 8 * CH + lane * 8;
        gll16(gs, &Gs[dbuf][wave * 8 * CH]);
        const unsigned short* gqs =
            Gq_all + ((size_t)b * NCH + chunk) * CH * CH + wave * 8 * CH + lane * 8;
        gll16(gqs, &Gqs[dbuf][wave * 8 * CH]);
        if (wave < 2) {
            const int t = wave * 32 + (lane >> 1);
            const float* src = a_all +
                ((size_t)(chunk * CH + t) * BB + b) * NN + r0 + (lane & 1) * 4;
            gll16(src, &asl[dbuf][wave * 256]);
        } else if (wave < 4) {
            const int t = (wave - 2) * 32 + (lane >> 1);
            const float* src = w_all +
                ((size_t)(chunk * CH + t) * BB + b) * NN + r0 + (lane & 1) * 4;
            gll16(src, &wsl[dbuf][(wave - 2) * 256]);
        }
    };

    // --- k/q staging: global f32 -> VGPR -> bf16 -> padded LDS (single buf) ---
    const int st_row = wave * 8 + (lane >> 3);   // 0..63
    const int st_col = (lane & 7) * 8;           // 0..56
    float4 kp0, kp1, qp0, qp1;
    auto load_kq = [&](int chunk) {
        const size_t g = ((size_t)(chunk * CH + st_row) * BB + b) * NN + st_col;
        kp0 = *(const float4*)(k_all + g);
        kp1 = *(const float4*)(k_all + g + 4);
        qp0 = *(const float4*)(q_all + g);
        qp1 = *(const float4*)(q_all + g + 4);
    };
    auto write_kq = [&]() {
        const int hb = st_row * 68 + st_col;   // halfword index, 8B-aligned
        *(uint2*)&ksb[hb]     = make_uint2(pack_bf16x2(kp0.x, kp0.y),
                                          pack_bf16x2(kp0.z, kp0.w));
        *(uint2*)&ksb[hb + 4] = make_uint2(pack_bf16x2(kp1.x, kp1.y),
                                          pack_bf16x2(kp1.z, kp1.w));
        *(uint2*)&qsb[hb]     = make_uint2(pack_bf16x2(qp0.x, qp0.y),
                                          pack_bf16x2(qp0.z, qp0.w));
        *(uint2*)&qsb[hb + 4] = make_uint2(pack_bf16x2(qp1.x, qp1.y),
                                          pack_bf16x2(qp1.z, qp1.w));
    };

    // prologue: chunk 0
    stage_G(0, 0);
    load_kq(0);
    write_kq();

    for (int c = 0; c < NCH; ++c) {
        const int cb = c & 1;
        __syncthreads();   // chunk-c G/Gq/a/w (gll16 drained) + k/q writes visible

        // --- per-chunk B0/qB0: column matvec, lane t accumulates S0 . k_t ---
        float B0a = 0.f, qB0a = 0.f;
        #pragma unroll 8
        for (int j = 0; j < CH; ++j) {
            const float sj = rdlane(S, j);
            B0a  = fmaf(sj, bf2f(ksb[lane * 68 + j]), B0a);
            qB0a = fmaf(sj, bf2f(qsb[lane * 68 + j]), qB0a);
        }

        if (c + 1 < NCH) { stage_G(c + 1, cb ^ 1); load_kq(c + 1); }

        const float areg = asl[cb][lane * 8 + wave];   // a_t at lane t
        const float wreg = wsl[cb][lane * 8 + wave];   // w_t at lane t
        const unsigned short* Gb  = &Gs [cb][0];
        const unsigned short* Gqb = &Gqs[cb][0];

        // --- serial recurrence: no cross-lane reductions ---
        float acc_d = 0.f, acc_q = 0.f, acc_S = 0.f, A = 1.0f;
        float ovreg = 0.f;
        #pragma unroll 8
        for (int s = 0; s < CH; ++s) {
            const float gro = bf2f(Gb [s * CH + lane]);
            const float gqo = bf2f(Gqb[s * CH + lane]);
            const float kro = bf2f(ksb[s * 68 + lane]);
            const float d   = rdlane(acc_d, s);
            const float b0  = rdlane(B0a, s);
            const float rv  = fmaf(A, b0, d);
            const float g   = __builtin_amdgcn_rcpf(
                                  1.0f + __expf(fmaf(ndg, rv, nbg)));
            const float cc  = rdlane(wreg, s) * g;
            const float at  = rdlane(areg, s);
            acc_d = fmaf(at, acc_d, cc * gro);
            acc_q = fmaf(at, acc_q, cc * gqo);
            acc_S = fmaf(at, acc_S, cc * kro);
            A *= at;
            const float ov = fmaf(A, rdlane(qB0a, s), rdlane(acc_q, s));
            ovreg = (lane == s) ? ov : ovreg;   // ov is wave-uniform
        }
        S = fmaf(A, S, acc_S);

        // y epilogue: lane t -> step c*CH + t
        {
            const float ovl = ovreg;
            const float y = ovl * ovl * sigmoidf_(ovl);   // out * silu(out)
            out[((size_t)(c * CH + lane) * BB + b) * NN + row] = y;
        }

        __syncthreads();   // all waves done reading ksb/qsb rows
        if (c + 1 < NCH) write_kq();
    }

    S_final[((size_t)b * NN + row) * NN + lane] = S;
}

// ---------------------------------------------------------------------------
extern "C" void kernel_launch(void* const* d_in, const int* in_sizes, int n_in,
                              void* d_out, int out_size, void* d_ws, size_t ws_size,
                              hipStream_t stream) {
    const float* x       = (const float*)d_in[0];
    const float* S0      = (const float*)d_in[1];
    const float* W_k     = (const float*)d_in[2];
    const float* W_v     = (const float*)d_in[3];
    const float* W_q     = (const float*)d_in[4];
    const float* W_alpha = (const float*)d_in[5];
    const float* b_alpha = (const float*)d_in[6];
    const float* d_g     = (const float*)d_in[7];
    const float* b_g     = (const float*)d_in[8];
    float* out = (float*)d_out;

    const size_t arr = (size_t)TT * BB * NN;           // 1M floats = 4 MB
    float* ws     = (float*)d_ws;
    float* k_all  = ws;
    float* v_all  = ws + arr;        // becomes w = (1-alpha)*v after prep
    float* q_all  = ws + 2 * arr;
    float* a_all  = ws + 3 * arr;
    unsigned short* G_all  = (unsigned short*)(ws + 4 * arr);          // 2 MB
    unsigned short* Gq_all = G_all + (size_t)BB * NCH * CH * CH;       // 2 MB

    proj_gemm_kernel<<<dim3(4, TT * BB / 128), 256, 0, stream>>>(
        x, W_k, W_v, W_q, W_alpha, b_alpha, k_all, v_all, q_all, a_all);

    prep_kernel<<<dim3(TT * BB * NN / 256), 256, 0, stream>>>(v_all, a_all);

    gram_kernel<<<dim3(NCH, BB), 256, 0, stream>>>(k_all, q_all, G_all, Gq_all);

    scan_kernel<<<dim3(BB, 8), 512, 0, stream>>>(
        k_all, q_all, v_all, a_all, G_all, Gq_all, S0, d_g, b_g,
        out, out + (size_t)TT * BB * NN);
}